// Round 2
// baseline (187.098 us; speedup 1.0000x reference)
//
#include <hip/hip_runtime.h>
#include <hip/hip_bf16.h>
#include <stdint.h>

#define B_    8
#define CIN   64
#define COUT  64
#define NPATH 9
#define H_    128
#define W_    128
#define HW    16384
#define PTOT  131072   // B*H*W
#define NBIN  72       // NPATH * B_
#define MAXCHUNK 4096  // >= 2120 actual chunks
#define NCHUNKS 2120   // 131072/64 + 72 worst-case padding

typedef float  f32x4  __attribute__((ext_vector_type(4)));
typedef __bf16 bf16x8 __attribute__((ext_vector_type(8)));
typedef short  short8 __attribute__((ext_vector_type(8)));

__device__ __forceinline__ unsigned short f2bf(float f) {
    __bf16 b = (__bf16)f;
    return __builtin_bit_cast(unsigned short, b);
}

// ---------------------------------------------------------------- K0a:
// x (B,CIN,H,W) f32  ->  Xb (B,H,W,CIN) bf16   (LDS tile transpose)
__global__ void k_x_to_bf16_nhwc(const float* __restrict__ x,
                                 unsigned short* __restrict__ Xb) {
    __shared__ float tile[64][65];
    int b = blockIdx.z, h = blockIdx.y, w0 = blockIdx.x * 64;
    int t = threadIdx.x;
    #pragma unroll
    for (int i = 0; i < 16; ++i) {
        int f = i * 256 + t;
        int ci = f >> 6, w = f & 63;
        tile[ci][w] = x[((b * 64 + ci) * 128 + h) * 128 + w0 + w];
    }
    __syncthreads();
    #pragma unroll
    for (int i = 0; i < 16; ++i) {
        int f = i * 256 + t;
        int w = f >> 6, ci = f & 63;
        Xb[(((b * 128 + h) * 128) + w0 + w) * 64 + ci] = f2bf(tile[ci][w]);
    }
}

// ---------------------------------------------------------------- K0b:
// kernels_w (N,COUT,CIN,3,3) f32 -> Wb[n][c][tap][ci] bf16
__global__ void k_w_to_bf16(const float* __restrict__ kw,
                            unsigned short* __restrict__ Wb) {
    int o = blockIdx.x * 256 + threadIdx.x;     // 331776 total
    int ci  = o & 63;
    int r   = o >> 6;
    int tap = r % 9;
    int c   = (r / 9) & 63;
    int n   = r / 576;
    Wb[o] = f2bf(kw[(((n * 64 + c) * 64) + ci) * 9 + tap]);
}

// ---------------------------------------------------------------- K1:
// fp32 observer scores + argmax + ordered compaction into (path,batch) bins
__global__ void k_scores_bin(const float* __restrict__ x,
                             const float* __restrict__ w1, const float* __restrict__ b1,
                             const float* __restrict__ w2, const float* __restrict__ b2,
                             unsigned* __restrict__ gcnt, unsigned* __restrict__ lists) {
    __shared__ float sw1[2048];   // [32][64]
    __shared__ float sw2[288];    // [9][32]
    __shared__ float sb1[32];
    __shared__ float sb2[9];
    __shared__ unsigned scnt[NBIN];
    __shared__ unsigned sbase[NBIN];
    int t = threadIdx.x;
    #pragma unroll
    for (int i = 0; i < 8; ++i) sw1[t + i * 256] = w1[t + i * 256];
    for (int i = t; i < 288; i += 256) sw2[i] = w2[i];
    if (t < 32) sb1[t] = b1[t];
    if (t < 9)  sb2[t] = b2[t];
    if (t < NBIN) scnt[t] = 0u;
    __syncthreads();

    int p  = blockIdx.x * 256 + t;
    int b  = p >> 14;
    const float* xp = x + (size_t)b * 64 * HW + (p & 16383);
    float xv[64];
    #pragma unroll
    for (int ci = 0; ci < 64; ++ci) xv[ci] = xp[ci * HW];

    float s[9];
    #pragma unroll
    for (int nn = 0; nn < 9; ++nn) s[nn] = sb2[nn];

    for (int j = 0; j < 32; ++j) {
        float a = sb1[j];
        const float4* wv = (const float4*)&sw1[j * 64];
        #pragma unroll
        for (int q = 0; q < 16; ++q) {
            float4 v = wv[q];
            a += xv[q*4+0]*v.x + xv[q*4+1]*v.y + xv[q*4+2]*v.z + xv[q*4+3]*v.w;
        }
        float hsig = tanhf(a);
        #pragma unroll
        for (int nn = 0; nn < 9; ++nn) s[nn] += hsig * sw2[nn * 32 + j];
    }
    float best = s[0]; int bi = 0;
    #pragma unroll
    for (int nn = 1; nn < 9; ++nn) if (s[nn] > best) { best = s[nn]; bi = nn; }

    int bin = bi * 8 + b;
    unsigned rank = atomicAdd(&scnt[bin], 1u);
    __syncthreads();
    if (t < NBIN && scnt[t]) sbase[t] = atomicAdd(&gcnt[t], scnt[t]);
    __syncthreads();
    lists[bin * 16384 + sbase[bin] + rank] = (unsigned)p;
}

// ---------------------------------------------------------------- K1b:
// prefix sum over bins (64-aligned) + chunk->bin table
__global__ void k_prefix(const unsigned* __restrict__ gcnt, unsigned* __restrict__ binstart,
                         unsigned* __restrict__ chunktab) {
    __shared__ unsigned st[NBIN + 1];
    int t = threadIdx.x;
    for (int i = t; i < MAXCHUNK; i += 256) chunktab[i] = 0xFFFFFFFFu;
    if (t == 0) {
        unsigned acc = 0;
        for (int bin = 0; bin < NBIN; ++bin) {
            st[bin] = acc;
            acc += ((gcnt[bin] + 63u) >> 6) << 6;
        }
        st[NBIN] = acc;
    }
    __syncthreads();
    if (t <= NBIN) binstart[t] = st[t];
    if (t < NBIN) {
        unsigned c0 = st[t] >> 6, c1 = st[t + 1] >> 6;
        for (unsigned k = c0; k < c1; ++k) chunktab[k] = (unsigned)t;
    }
}

// ---------------------------------------------------------------- K1c:
// inverse map pixel -> global slot
__global__ void k_inv(const unsigned* __restrict__ gcnt, const unsigned* __restrict__ binstart,
                      const unsigned* __restrict__ lists, unsigned* __restrict__ inv) {
    int bin = blockIdx.x;
    unsigned pos = blockIdx.y * 256 + threadIdx.x;
    if (pos < gcnt[bin]) inv[lists[bin * 16384 + pos]] = binstart[bin] + pos;
}

// ---------------------------------------------------------------- K2:
// gathered implicit-GEMM selected conv -> compact Yc[slot][c], fused IN stats
__global__ __launch_bounds__(256) void k_conv(
        const unsigned short* __restrict__ Xb, const unsigned short* __restrict__ Wb,
        const float* __restrict__ kb, const unsigned* __restrict__ gcnt,
        const unsigned* __restrict__ binstart, const unsigned* __restrict__ chunktab,
        const unsigned* __restrict__ lists, float* __restrict__ Yc,
        float* __restrict__ sums) {
    __shared__ float lsum[64], lsq[64];
    int t = threadIdx.x;
    if (t < 64) { lsum[t] = 0.f; lsq[t] = 0.f; }
    unsigned bin = chunktab[blockIdx.x];
    if (bin == 0xFFFFFFFFu) return;
    int n = bin >> 3, b = bin & 7;
    unsigned cnt = gcnt[bin];
    int local_base = (int)(blockIdx.x * 64u - binstart[bin]);
    int wid = t >> 6, lane = t & 63, kg = lane >> 4, l15 = lane & 15;
    int pidx = local_base + wid * 16 + l15;
    int valid = pidx < (int)cnt;
    int pclamp = valid ? pidx : (int)cnt - 1;
    unsigned p = lists[bin * 16384 + pclamp];
    int h = (p >> 7) & 127, w = p & 127;
    const unsigned short* xrow  = Xb + ((size_t)((b * 128 + h) * 128 + w) << 6);
    const unsigned short* wbase = Wb + n * 36864;     // [c][tap][ci]

    f32x4 acc[4];
    #pragma unroll
    for (int f = 0; f < 4; ++f) acc[f] = (f32x4)0.0f;

    #pragma unroll
    for (int s = 0; s < 18; ++s) {
        int tap = s >> 1;
        int dh = tap / 3 - 1, dw = tap % 3 - 1;
        int co = ((s & 1) << 5) + (kg << 3);
        int h2 = h + dh, w2 = w + dw;
        short8 braw = ((unsigned)h2 < 128u && (unsigned)w2 < 128u)
                      ? *(const short8*)(xrow + ((dh * 128 + dw) << 6) + co) : (short8)0;
        bf16x8 bb = __builtin_bit_cast(bf16x8, braw);
        #pragma unroll
        for (int f = 0; f < 4; ++f) {
            short8 araw = *(const short8*)(wbase + (f * 16 + l15) * 576 + (tap << 6) + co);
            acc[f] = __builtin_amdgcn_mfma_f32_16x16x32_bf16(
                         __builtin_bit_cast(bf16x8, araw), bb, acc[f], 0, 0, 0);
        }
    }

    __syncthreads();   // lsum/lsq init visible before LDS atomics

    size_t yrow = ((size_t)blockIdx.x * 64 + wid * 16 + l15) << 6;
    float s1[16], s2[16];
    #pragma unroll
    for (int f = 0; f < 4; ++f) {
        #pragma unroll
        for (int r = 0; r < 4; ++r) {
            int c = f * 16 + (kg << 2) + r;
            float v = acc[f][r] + kb[n * 64 + c];
            v = fmaxf(v, 0.0f);
            if (valid) Yc[yrow + c] = v;
            float sv = valid ? v : 0.0f;
            s1[f * 4 + r] = sv;
            s2[f * 4 + r] = sv * sv;
        }
    }
    #pragma unroll
    for (int m = 1; m < 16; m <<= 1) {
        #pragma unroll
        for (int i = 0; i < 16; ++i) {
            s1[i] += __shfl_xor(s1[i], m, 64);
            s2[i] += __shfl_xor(s2[i], m, 64);
        }
    }
    if (l15 == 0) {
        #pragma unroll
        for (int i = 0; i < 16; ++i) {
            int c = (i >> 2) * 16 + (kg << 2) + (i & 3);
            atomicAdd(&lsum[c], s1[i]);
            atomicAdd(&lsq[c],  s2[i]);
        }
    }
    __syncthreads();
    if (t < 64) {
        atomicAdd(&sums[b * 64 + t],       lsum[t]);
        atomicAdd(&sums[512 + b * 64 + t], lsq[t]);
    }
}

// ---------------------------------------------------------------- K3:
// gather Yc rows -> LDS transpose -> normalized coalesced NCHW store
__global__ void k_final(const float* __restrict__ Yc, const unsigned* __restrict__ inv,
                        const float* __restrict__ sums, const float* __restrict__ gamma,
                        const float* __restrict__ beta, float* __restrict__ out) {
    __shared__ float ld[128][66];
    __shared__ float smu[64], srs[64], sg[64], sb[64];
    int t = threadIdx.x;
    int b = blockIdx.y, hw0 = blockIdx.x * 128;
    if (t < 64) {
        float mu = sums[b * 64 + t] * (1.0f / HW);
        float vr = sums[512 + b * 64 + t] * (1.0f / HW) - mu * mu;
        smu[t] = mu;
        srs[t] = rsqrtf(fmaxf(vr, 0.0f) + 1e-5f);
        sg[t] = gamma[t]; sb[t] = beta[t];
    }
    int i = t >> 1, half = t & 1;
    unsigned slot = inv[b * HW + hw0 + i];
    const float4* row = (const float4*)(Yc + ((size_t)slot << 6) + half * 32);
    #pragma unroll
    for (int q = 0; q < 8; ++q) {
        float4 v = row[q];
        float2* d = (float2*)&ld[i][half * 32 + 4 * q];
        d[0] = make_float2(v.x, v.y);
        d[1] = make_float2(v.z, v.w);
    }
    __syncthreads();
    #pragma unroll
    for (int rep = 0; rep < 32; ++rep) {
        int idx = rep * 256 + t;          // 8192 = 64c x 128hw
        int c = idx >> 7, j = idx & 127;
        float v = (ld[j][c] - smu[c]) * srs[c] * sg[c] + sb[c];
        out[(((size_t)b * 64 + c) << 14) + hw0 + j] = v;
    }
}

extern "C" void kernel_launch(void* const* d_in, const int* in_sizes, int n_in,
                              void* d_out, int out_size, void* d_ws, size_t ws_size,
                              hipStream_t stream) {
    const float* x    = (const float*)d_in[0];
    const float* kw   = (const float*)d_in[1];
    const float* kb   = (const float*)d_in[2];
    const float* w1   = (const float*)d_in[3];
    const float* b1   = (const float*)d_in[4];
    const float* w2   = (const float*)d_in[5];
    const float* b2   = (const float*)d_in[6];
    const float* gam  = (const float*)d_in[7];
    const float* bet  = (const float*)d_in[8];
    float* out = (float*)d_out;

    char* ws = (char*)d_ws;
    unsigned* gcnt      = (unsigned*)(ws + 0);          // 72 u32
    unsigned* binstart  = (unsigned*)(ws + 512);        // 73 u32
    unsigned* chunktab  = (unsigned*)(ws + 1024);       // 4096 u32
    float*    sums      = (float*)   (ws + 17408);      // 1024 f32
    unsigned* inv       = (unsigned*)(ws + 32768);      // 131072 u32
    unsigned* lists     = (unsigned*)(ws + 557056);     // 72*16384 u32
    float*    Yc        = (float*)   (ws + 5275648);    // 135680*64 f32 (34.7 MB)
    unsigned short* Xb  = (unsigned short*)(ws + 40009728); // 16.8 MB
    unsigned short* Wb  = (unsigned short*)(ws + 56786944); // 0.66 MB
    // total ws usage ~57.5 MB

    hipMemsetAsync(gcnt, 0, 512, stream);
    hipMemsetAsync(sums, 0, 4096, stream);
    k_x_to_bf16_nhwc<<<dim3(2, 128, 8), 256, 0, stream>>>(x, Xb);
    k_w_to_bf16<<<1296, 256, 0, stream>>>(kw, Wb);
    k_scores_bin<<<512, 256, 0, stream>>>(x, w1, b1, w2, b2, gcnt, lists);
    k_prefix<<<1, 256, 0, stream>>>(gcnt, binstart, chunktab);
    k_inv<<<dim3(72, 64), 256, 0, stream>>>(gcnt, binstart, lists, inv);
    k_conv<<<NCHUNKS, 256, 0, stream>>>(Xb, Wb, kb, gcnt, binstart, chunktab, lists, Yc, sums);
    k_final<<<dim3(128, 8), 256, 0, stream>>>(Yc, inv, sums, gam, bet, out);
}

// Round 3
// 107.846 us; speedup vs baseline: 1.7349x; 1.7349x over previous
//
#include <hip/hip_runtime.h>
#include <hip/hip_bf16.h>
#include <stdint.h>

#define B_    8
#define CIN   64
#define COUT  64
#define NPATH 9
#define H_    128
#define W_    128
#define HW    16384
#define PTOT  131072   // B*H*W
#define NBIN  72       // NPATH * B_
#define CHUNK 256      // pixels per k_conv block
#define NCHUNKS 584    // 131072/256 + 72 (worst-case padding)
#define MAXCHUNK 1024
#define LROW  1168     // padded LDS row stride (1152 + 16)

typedef float  f32x4  __attribute__((ext_vector_type(4)));
typedef __bf16 bf16x8 __attribute__((ext_vector_type(8)));
typedef short  short8 __attribute__((ext_vector_type(8)));

__device__ __forceinline__ short f2bf(float f) {
    __bf16 b = (__bf16)f;
    return __builtin_bit_cast(short, b);
}

// ---------------------------------------------------------------- K0b:
// kernels_w (N,COUT,CIN,3,3) f32 -> Wb[n][c][tap][ci] bf16
__global__ void k_w_to_bf16(const float* __restrict__ kw,
                            unsigned short* __restrict__ Wb) {
    int o = blockIdx.x * 256 + threadIdx.x;     // 331776 total
    int ci  = o & 63;
    int r   = o >> 6;
    int tap = r % 9;
    int c   = (r / 9) & 63;
    int n   = r / 576;
    Wb[o] = (unsigned short)f2bf(kw[(((n * 64 + c) * 64) + ci) * 9 + tap]);
}

// ---------------------------------------------------------------- K1:
// fp32 observer scores + argmax + compaction; ALSO emits Xb bf16 NHWC
__global__ void k_scores_bin(const float* __restrict__ x,
                             const float* __restrict__ w1, const float* __restrict__ b1,
                             const float* __restrict__ w2, const float* __restrict__ b2,
                             unsigned* __restrict__ gcnt, unsigned* __restrict__ lists,
                             unsigned short* __restrict__ Xb) {
    __shared__ float sw1[2048];   // [32][64]
    __shared__ float sw2[288];    // [9][32]
    __shared__ float sb1[32];
    __shared__ float sb2[9];
    __shared__ unsigned scnt[NBIN];
    __shared__ unsigned sbase[NBIN];
    int t = threadIdx.x;
    #pragma unroll
    for (int i = 0; i < 8; ++i) sw1[t + i * 256] = w1[t + i * 256];
    for (int i = t; i < 288; i += 256) sw2[i] = w2[i];
    if (t < 32) sb1[t] = b1[t];
    if (t < 9)  sb2[t] = b2[t];
    if (t < NBIN) scnt[t] = 0u;
    __syncthreads();

    int p  = blockIdx.x * 256 + t;
    int b  = p >> 14;
    const float* xp = x + (size_t)b * 64 * HW + (p & 16383);
    float xv[64];
    #pragma unroll
    for (int ci = 0; ci < 64; ++ci) xv[ci] = xp[ci * HW];

    // emit bf16 NHWC row for this pixel (contiguous 128 B across thread-consecutive rows)
    #pragma unroll
    for (int j = 0; j < 8; ++j) {
        short8 v;
        #pragma unroll
        for (int q = 0; q < 8; ++q) v[q] = f2bf(xv[j * 8 + q]);
        *(short8*)(Xb + (((size_t)p) << 6) + j * 8) = v;
    }

    float s[9];
    #pragma unroll
    for (int nn = 0; nn < 9; ++nn) s[nn] = sb2[nn];

    for (int j = 0; j < 32; ++j) {
        float a = sb1[j];
        const float4* wv = (const float4*)&sw1[j * 64];
        #pragma unroll
        for (int q = 0; q < 16; ++q) {
            float4 v = wv[q];
            a += xv[q*4+0]*v.x + xv[q*4+1]*v.y + xv[q*4+2]*v.z + xv[q*4+3]*v.w;
        }
        float hsig = tanhf(a);
        #pragma unroll
        for (int nn = 0; nn < 9; ++nn) s[nn] += hsig * sw2[nn * 32 + j];
    }
    float best = s[0]; int bi = 0;
    #pragma unroll
    for (int nn = 1; nn < 9; ++nn) if (s[nn] > best) { best = s[nn]; bi = nn; }

    int bin = bi * 8 + b;
    unsigned rank = atomicAdd(&scnt[bin], 1u);
    __syncthreads();
    if (t < NBIN && scnt[t]) sbase[t] = atomicAdd(&gcnt[t], scnt[t]);
    __syncthreads();
    lists[bin * 16384 + sbase[bin] + rank] = (unsigned)p;
}

// ---------------------------------------------------------------- K1b:
// prefix sum over bins (CHUNK-aligned) + chunk->bin table
__global__ void k_prefix(const unsigned* __restrict__ gcnt, unsigned* __restrict__ binstart,
                         unsigned* __restrict__ chunktab) {
    __shared__ unsigned st[NBIN + 1];
    int t = threadIdx.x;
    for (int i = t; i < MAXCHUNK; i += 256) chunktab[i] = 0xFFFFFFFFu;
    if (t == 0) {
        unsigned acc = 0;
        for (int bin = 0; bin < NBIN; ++bin) {
            st[bin] = acc;
            acc += ((gcnt[bin] + (CHUNK - 1u)) / CHUNK) * CHUNK;
        }
        st[NBIN] = acc;
    }
    __syncthreads();
    if (t <= NBIN) binstart[t] = st[t];
    if (t < NBIN) {
        unsigned c0 = st[t] / CHUNK, c1 = st[t + 1] / CHUNK;
        for (unsigned k = c0; k < c1; ++k) chunktab[k] = (unsigned)t;
    }
}

// ---------------------------------------------------------------- K2:
// gathered implicit-GEMM selected conv (Wb staged in LDS, pipelined B-gather)
// 512 thr = 8 waves; wave handles 2 groups x 16 px, all 64 out channels.
// Writes pixel-indexed Yc[p][64] (full-line 256 B rows) + fused IN stats.
__global__ __launch_bounds__(512, 4) void k_conv(
        const unsigned short* __restrict__ Xb, const unsigned short* __restrict__ Wb,
        const float* __restrict__ kb, const unsigned* __restrict__ gcnt,
        const unsigned* __restrict__ binstart, const unsigned* __restrict__ chunktab,
        const unsigned* __restrict__ lists, float* __restrict__ Yc,
        float* __restrict__ sums) {
    __shared__ char wlds[64 * LROW];          // 74752 B padded weight tile
    __shared__ float lsum[64], lsq[64];
    int t = threadIdx.x;
    unsigned bin = chunktab[blockIdx.x];
    if (bin == 0xFFFFFFFFu) return;
    int n = bin >> 3, b = bin & 7;

    // ---- stage Wb[n] (36864 shorts) into padded LDS rows
    {
        const short8* src = (const short8*)(Wb + n * 36864);
        #pragma unroll
        for (int k = 0; k < 9; ++k) {
            int i = t + k * 512;              // 16B chunk id, 0..4607
            int c = i / 72;                   // row (out channel)
            int off = (i - c * 72) * 16;      // byte offset within row
            *(short8*)(&wlds[c * LROW + off]) = src[i];
        }
    }
    if (t < 64) { lsum[t] = 0.f; lsq[t] = 0.f; }
    __syncthreads();

    unsigned cnt = gcnt[bin];
    int local_base = (int)(blockIdx.x * (unsigned)CHUNK - binstart[bin]);
    int wid = t >> 6, lane = t & 63, kg = lane >> 4, l15 = lane & 15;

    int hh[2], ww[2], val[2];
    const short* xrow[2];
    size_t yb[2];
    #pragma unroll
    for (int g = 0; g < 2; ++g) {
        int pidx = local_base + wid * 32 + g * 16 + l15;
        val[g] = pidx < (int)cnt;
        int pcl = val[g] ? pidx : (int)cnt - 1;
        unsigned p = lists[bin * 16384 + pcl];
        int h = (p >> 7) & 127, w = p & 127;
        hh[g] = h; ww[g] = w;
        xrow[g] = (const short*)Xb + ((size_t)(((b * 128 + h) * 128) + w) << 6);
        yb[g] = ((size_t)p) << 6;
    }

    f32x4 acc[2][4];
    #pragma unroll
    for (int g = 0; g < 2; ++g)
        #pragma unroll
        for (int f = 0; f < 4; ++f) acc[g][f] = (f32x4)0.0f;

    // B-gather helper (masked; OOB lanes skip the load)
    #define GATHER(g, s) ({                                                     \
        const int tap_ = (s) >> 1;                                              \
        const int dh_ = tap_ / 3 - 1, dw_ = tap_ % 3 - 1;                       \
        int h2_ = hh[g] + dh_, w2_ = ww[g] + dw_;                               \
        int off_ = ((dh_ * 128 + dw_) << 6) + (((s) & 1) << 5) + (kg << 3);     \
        ((unsigned)h2_ < 128u && (unsigned)w2_ < 128u)                          \
            ? *(const short8*)(xrow[g] + off_) : (short8)0; })

    short8 bwin[2][4];
    #pragma unroll
    for (int s = 0; s < 4; ++s) {
        bwin[0][s] = GATHER(0, s);
        bwin[1][s] = GATHER(1, s);
    }

    #pragma unroll
    for (int s = 0; s < 18; ++s) {
        const int slot = s & 3;               // s%4, static under full unroll
        bf16x8 b0 = __builtin_bit_cast(bf16x8, bwin[0][slot]);
        bf16x8 b1 = __builtin_bit_cast(bf16x8, bwin[1][slot]);
        if (s + 4 < 18) {
            bwin[0][slot] = GATHER(0, s + 4);
            bwin[1][slot] = GATHER(1, s + 4);
        }
        const int tap = s >> 1;
        int abase = tap * 128 + ((s & 1) << 6) + (kg << 4);
        #pragma unroll
        for (int f = 0; f < 4; ++f) {
            short8 araw = *(const short8*)(&wlds[(f * 16 + l15) * LROW + abase]);
            bf16x8 af = __builtin_bit_cast(bf16x8, araw);
            acc[0][f] = __builtin_amdgcn_mfma_f32_16x16x32_bf16(af, b0, acc[0][f], 0, 0, 0);
            acc[1][f] = __builtin_amdgcn_mfma_f32_16x16x32_bf16(af, b1, acc[1][f], 0, 0, 0);
        }
    }
    #undef GATHER

    // ---- epilogue: bias + relu + Yc store + stats
    float s1[16], s2[16];
    #pragma unroll
    for (int i = 0; i < 16; ++i) { s1[i] = 0.f; s2[i] = 0.f; }
    #pragma unroll
    for (int g = 0; g < 2; ++g) {
        #pragma unroll
        for (int f = 0; f < 4; ++f) {
            f32x4 bias = *(const f32x4*)(kb + n * 64 + f * 16 + kg * 4);
            f32x4 v;
            #pragma unroll
            for (int r = 0; r < 4; ++r) v[r] = fmaxf(acc[g][f][r] + bias[r], 0.0f);
            if (val[g]) *(f32x4*)(Yc + yb[g] + f * 16 + kg * 4) = v;
            #pragma unroll
            for (int r = 0; r < 4; ++r) {
                float sv = val[g] ? v[r] : 0.0f;
                s1[f * 4 + r] += sv;
                s2[f * 4 + r] += sv * sv;
            }
        }
    }
    #pragma unroll
    for (int m = 1; m < 16; m <<= 1) {
        #pragma unroll
        for (int i = 0; i < 16; ++i) {
            s1[i] += __shfl_xor(s1[i], m, 64);
            s2[i] += __shfl_xor(s2[i], m, 64);
        }
    }
    if (l15 == 0) {
        #pragma unroll
        for (int i = 0; i < 16; ++i) {
            int c = (i >> 2) * 16 + (kg << 2) + (i & 3);
            atomicAdd(&lsum[c], s1[i]);
            atomicAdd(&lsq[c],  s2[i]);
        }
    }
    __syncthreads();
    if (t < 64) {
        atomicAdd(&sums[b * 64 + t],       lsum[t]);
        atomicAdd(&sums[512 + b * 64 + t], lsq[t]);
    }
}

// ---------------------------------------------------------------- K3:
// contiguous Yc rows -> LDS transpose -> normalized coalesced NCHW store
__global__ void k_final(const float* __restrict__ Yc, const float* __restrict__ sums,
                        const float* __restrict__ gamma, const float* __restrict__ beta,
                        float* __restrict__ out) {
    __shared__ float ld[128][66];
    __shared__ float smu[64], srs[64], sg[64], sb[64];
    int t = threadIdx.x;
    int b = blockIdx.y, hw0 = blockIdx.x * 128;
    if (t < 64) {
        float mu = sums[b * 64 + t] * (1.0f / HW);
        float vr = sums[512 + b * 64 + t] * (1.0f / HW) - mu * mu;
        smu[t] = mu;
        srs[t] = rsqrtf(fmaxf(vr, 0.0f) + 1e-5f);
        sg[t] = gamma[t]; sb[t] = beta[t];
    }
    int i = t >> 1, half = t & 1;
    const float4* row = (const float4*)(Yc + (((size_t)(b * HW + hw0 + i)) << 6) + half * 32);
    #pragma unroll
    for (int q = 0; q < 8; ++q) {
        float4 v = row[q];
        float2* d = (float2*)&ld[i][half * 32 + 4 * q];
        d[0] = make_float2(v.x, v.y);
        d[1] = make_float2(v.z, v.w);
    }
    __syncthreads();
    #pragma unroll
    for (int rep = 0; rep < 32; ++rep) {
        int idx = rep * 256 + t;          // 8192 = 64c x 128hw
        int c = idx >> 7, j = idx & 127;
        float v = (ld[j][c] - smu[c]) * srs[c] * sg[c] + sb[c];
        out[(((size_t)b * 64 + c) << 14) + hw0 + j] = v;
    }
}

extern "C" void kernel_launch(void* const* d_in, const int* in_sizes, int n_in,
                              void* d_out, int out_size, void* d_ws, size_t ws_size,
                              hipStream_t stream) {
    const float* x    = (const float*)d_in[0];
    const float* kw   = (const float*)d_in[1];
    const float* kb   = (const float*)d_in[2];
    const float* w1   = (const float*)d_in[3];
    const float* b1   = (const float*)d_in[4];
    const float* w2   = (const float*)d_in[5];
    const float* b2   = (const float*)d_in[6];
    const float* gam  = (const float*)d_in[7];
    const float* bet  = (const float*)d_in[8];
    float* out = (float*)d_out;

    char* ws = (char*)d_ws;
    unsigned* gcnt      = (unsigned*)(ws + 0);          // 72 u32
    unsigned* binstart  = (unsigned*)(ws + 512);        // 73 u32
    unsigned* chunktab  = (unsigned*)(ws + 1024);       // 1024 u32
    float*    sums      = (float*)   (ws + 8192);       // 1024 f32
    unsigned* lists     = (unsigned*)(ws + 16384);      // 72*16384 u32 (4.72 MB)
    float*    Yc        = (float*)   (ws + 5242880);    // 131072*64 f32 (33.55 MB)
    unsigned short* Xb  = (unsigned short*)(ws + 38797312); // 16.78 MB
    unsigned short* Wb  = (unsigned short*)(ws + 55574528); // 0.66 MB
    // total ws usage ~56.3 MB

    hipMemsetAsync(gcnt, 0, 512, stream);
    hipMemsetAsync(sums, 0, 4096, stream);
    k_w_to_bf16<<<1296, 256, 0, stream>>>(kw, Wb);
    k_scores_bin<<<512, 256, 0, stream>>>(x, w1, b1, w2, b2, gcnt, lists, Xb);
    k_prefix<<<1, 256, 0, stream>>>(gcnt, binstart, chunktab);
    k_conv<<<NCHUNKS, 512, 0, stream>>>(Xb, Wb, kb, gcnt, binstart, chunktab, lists, Yc, sums);
    k_final<<<dim3(128, 8), 256, 0, stream>>>(Yc, sums, gam, bet, out);
}